// Round 1
// baseline (1196.734 us; speedup 1.0000x reference)
//
#include <hip/hip_runtime.h>

#define NN 131072
#define NE 1048576
#define DD 64
#define NG 32
#define NPG (NN / NG)  // 4096 nodes per graph

// ---------------- degree histogram ----------------
extern "C" __global__ void k_count(const int* __restrict__ col, int* __restrict__ cnt) {
  int e = blockIdx.x * 256 + threadIdx.x;
  if (e < NE) atomicAdd(&cnt[col[e]], 1);
}

extern "C" __global__ void k_dis(const int* __restrict__ cnt, float* __restrict__ dis) {
  int i = blockIdx.x * 256 + threadIdx.x;
  if (i < NN) dis[i] = rsqrtf((float)cnt[i] + 1.0f);
}

// ---------------- GEMM1: h1 = x @ W1 ; agg1 = h1 * dis^2 (self-loop init) ----------------
extern "C" __global__ __launch_bounds__(256) void k_gemm1(
    const float* __restrict__ x, const float* __restrict__ W1,
    const float* __restrict__ dis, float* __restrict__ h1, float* __restrict__ agg1) {
  __shared__ float4 wl[DD * 16];  // W1 as [k][j4], 16 KB
  int t = threadIdx.x;
  for (int i = t; i < DD * 16; i += 256) wl[i] = reinterpret_cast<const float4*>(W1)[i];
  __syncthreads();
  int row = blockIdx.x * 256 + t;
  const float4* xp = reinterpret_cast<const float4*>(x + (size_t)row * DD);
  float4 acc[16];
#pragma unroll
  for (int j = 0; j < 16; ++j) acc[j] = make_float4(0.f, 0.f, 0.f, 0.f);
#pragma unroll
  for (int kk = 0; kk < 16; ++kk) {
    float4 a = xp[kk];
#pragma unroll
    for (int j = 0; j < 16; ++j) {
      float4 w0 = wl[(4 * kk + 0) * 16 + j];
      float4 w1 = wl[(4 * kk + 1) * 16 + j];
      float4 w2 = wl[(4 * kk + 2) * 16 + j];
      float4 w3 = wl[(4 * kk + 3) * 16 + j];
      acc[j].x += a.x * w0.x + a.y * w1.x + a.z * w2.x + a.w * w3.x;
      acc[j].y += a.x * w0.y + a.y * w1.y + a.z * w2.y + a.w * w3.y;
      acc[j].z += a.x * w0.z + a.y * w1.z + a.z * w2.z + a.w * w3.z;
      acc[j].w += a.x * w0.w + a.y * w1.w + a.z * w2.w + a.w * w3.w;
    }
  }
  float s = dis[row];
  s = s * s;
  float4* hp = reinterpret_cast<float4*>(h1 + (size_t)row * DD);
  float4* ap = reinterpret_cast<float4*>(agg1 + (size_t)row * DD);
#pragma unroll
  for (int j = 0; j < 16; ++j) {
    float4 v = acc[j];
    hp[j] = v;
    v.x *= s; v.y *= s; v.z *= s; v.w *= s;
    ap[j] = v;
  }
}

// ---------------- edge scatter layer 1: agg1[col] += h1[row] * norm ----------------
extern "C" __global__ void k_edge1(const int* __restrict__ row, const int* __restrict__ col,
                                   const float* __restrict__ dis, const float* __restrict__ h1,
                                   float* __restrict__ agg1) {
  int gid = blockIdx.x * 256 + threadIdx.x;  // max 16.7M, fits int
  int e = gid >> 4;
  int part = gid & 15;
  if (e < NE) {
    int r = row[e], c = col[e];
    float norm = dis[r] * dis[c];
    float4 v = reinterpret_cast<const float4*>(h1 + (size_t)r * DD)[part];
    float* dst = agg1 + (size_t)c * DD + part * 4;
    unsafeAtomicAdd(dst + 0, v.x * norm);
    unsafeAtomicAdd(dst + 1, v.y * norm);
    unsafeAtomicAdd(dst + 2, v.z * norm);
    unsafeAtomicAdd(dst + 3, v.w * norm);
  }
}

// ---------------- layer2: z = relu(agg1 + b1); h2 = z @ W2; agg2 = h2 * dis^2 ----------------
extern "C" __global__ __launch_bounds__(256) void k_layer2(
    const float* __restrict__ agg1, const float* __restrict__ b1,
    const float* __restrict__ W2, const float* __restrict__ dis,
    float* __restrict__ h2, float* __restrict__ agg2) {
  __shared__ float w2l[DD * 3];
  __shared__ float b1l[DD];
  int t = threadIdx.x;
  if (t < DD * 3) w2l[t] = W2[t];
  if (t < DD) b1l[t] = b1[t];
  __syncthreads();
  int row = blockIdx.x * 256 + t;
  const float4* zp = reinterpret_cast<const float4*>(agg1 + (size_t)row * DD);
  float a0 = 0.f, a1 = 0.f, a2 = 0.f;
#pragma unroll
  for (int kk = 0; kk < 16; ++kk) {
    float4 z = zp[kk];
    float z0 = fmaxf(z.x + b1l[4 * kk + 0], 0.f);
    float z1 = fmaxf(z.y + b1l[4 * kk + 1], 0.f);
    float z2 = fmaxf(z.z + b1l[4 * kk + 2], 0.f);
    float z3 = fmaxf(z.w + b1l[4 * kk + 3], 0.f);
    a0 += z0 * w2l[(4 * kk + 0) * 3 + 0] + z1 * w2l[(4 * kk + 1) * 3 + 0] +
          z2 * w2l[(4 * kk + 2) * 3 + 0] + z3 * w2l[(4 * kk + 3) * 3 + 0];
    a1 += z0 * w2l[(4 * kk + 0) * 3 + 1] + z1 * w2l[(4 * kk + 1) * 3 + 1] +
          z2 * w2l[(4 * kk + 2) * 3 + 1] + z3 * w2l[(4 * kk + 3) * 3 + 1];
    a2 += z0 * w2l[(4 * kk + 0) * 3 + 2] + z1 * w2l[(4 * kk + 1) * 3 + 2] +
          z2 * w2l[(4 * kk + 2) * 3 + 2] + z3 * w2l[(4 * kk + 3) * 3 + 2];
  }
  float s = dis[row];
  s = s * s;
  h2[row * 3 + 0] = a0;
  h2[row * 3 + 1] = a1;
  h2[row * 3 + 2] = a2;
  agg2[row * 3 + 0] = a0 * s;
  agg2[row * 3 + 1] = a1 * s;
  agg2[row * 3 + 2] = a2 * s;
}

// ---------------- edge scatter layer 2 ----------------
extern "C" __global__ void k_edge2(const int* __restrict__ row, const int* __restrict__ col,
                                   const float* __restrict__ dis, const float* __restrict__ h2,
                                   float* __restrict__ agg2) {
  int e = blockIdx.x * 256 + threadIdx.x;
  if (e < NE) {
    int r = row[e], c = col[e];
    float norm = dis[r] * dis[c];
    unsafeAtomicAdd(&agg2[c * 3 + 0], h2[r * 3 + 0] * norm);
    unsafeAtomicAdd(&agg2[c * 3 + 1], h2[r * 3 + 1] * norm);
    unsafeAtomicAdd(&agg2[c * 3 + 2], h2[r * 3 + 2] * norm);
  }
}

// ---------------- mean pool over contiguous 4096-node graphs + b2 ----------------
extern "C" __global__ __launch_bounds__(256) void k_pool(
    const float* __restrict__ agg2, const float* __restrict__ b2, float* __restrict__ out) {
  __shared__ float red[3][256];
  int g = blockIdx.x, t = threadIdx.x;
  float s0 = 0.f, s1 = 0.f, s2 = 0.f;
  for (int n = t; n < NPG; n += 256) {
    int i = g * NPG + n;
    s0 += agg2[i * 3 + 0];
    s1 += agg2[i * 3 + 1];
    s2 += agg2[i * 3 + 2];
  }
  red[0][t] = s0; red[1][t] = s1; red[2][t] = s2;
  __syncthreads();
  for (int off = 128; off > 0; off >>= 1) {
    if (t < off) {
      red[0][t] += red[0][t + off];
      red[1][t] += red[1][t + off];
      red[2][t] += red[2][t + off];
    }
    __syncthreads();
  }
  if (t == 0) {
    float inv = 1.0f / (float)NPG;
    out[g * 3 + 0] = red[0][0] * inv + b2[0];
    out[g * 3 + 1] = red[1][0] * inv + b2[1];
    out[g * 3 + 2] = red[2][0] * inv + b2[2];
  }
}

extern "C" void kernel_launch(void* const* d_in, const int* in_sizes, int n_in,
                              void* d_out, int out_size, void* d_ws, size_t ws_size,
                              hipStream_t stream) {
  const float* x  = (const float*)d_in[0];
  const int*   ei = (const int*)d_in[1];   // [2, NE], int32 per harness convention
  const float* W1 = (const float*)d_in[3];
  const float* b1 = (const float*)d_in[4];
  const float* W2 = (const float*)d_in[5];
  const float* b2 = (const float*)d_in[6];
  const int* row = ei;
  const int* col = ei + NE;
  float* out = (float*)d_out;

  // workspace layout (bytes): cnt 512K | dis 512K | h1 32M | agg1 32M | h2 1.5M | agg2 1.5M
  char* ws = (char*)d_ws;
  int*   cnt  = (int*)ws;
  float* dis  = (float*)(ws + 524288);
  float* h1   = (float*)(ws + 1048576);
  float* agg1 = (float*)(ws + 1048576 + 33554432);
  float* h2   = (float*)(ws + 1048576 + 2 * 33554432);
  float* agg2 = (float*)(ws + 1048576 + 2 * 33554432 + 1572864);

  hipMemsetAsync(cnt, 0, NN * sizeof(int), stream);
  k_count<<<NE / 256, 256, 0, stream>>>(col, cnt);
  k_dis<<<NN / 256, 256, 0, stream>>>(cnt, dis);
  k_gemm1<<<NN / 256, 256, 0, stream>>>(x, W1, dis, h1, agg1);
  k_edge1<<<(NE * 16) / 256, 256, 0, stream>>>(row, col, dis, h1, agg1);
  k_layer2<<<NN / 256, 256, 0, stream>>>(agg1, b1, W2, dis, h2, agg2);
  k_edge2<<<NE / 256, 256, 0, stream>>>(row, col, dis, h2, agg2);
  k_pool<<<NG, 256, 0, stream>>>(agg2, b2, out);
}

// Round 2
// 268.527 us; speedup vs baseline: 4.4567x; 4.4567x over previous
//
#include <hip/hip_runtime.h>

#define NN 131072
#define NE 1048576
#define DD 64
#define NG 32
#define NPG 4096
#define SCAN_B 512  // 512 blocks x 256 = 131072

// ---------------- degree histogram ----------------
extern "C" __global__ void k_count(const int* __restrict__ col, int* __restrict__ cnt) {
  int e = blockIdx.x * 256 + threadIdx.x;
  if (e < NE) atomicAdd(&cnt[col[e]], 1);
}

extern "C" __global__ void k_dis(const int* __restrict__ cnt, float* __restrict__ dis) {
  int i = blockIdx.x * 256 + threadIdx.x;
  if (i < NN) dis[i] = rsqrtf((float)cnt[i] + 1.0f);
}

// ---------------- exclusive scan of cnt -> starts (3 phases) ----------------
extern "C" __global__ __launch_bounds__(256) void k_scan1(const int* __restrict__ cnt,
                                                          int* __restrict__ partial) {
  __shared__ int s[256];
  int t = threadIdx.x;
  s[t] = cnt[blockIdx.x * 256 + t];
  __syncthreads();
  for (int off = 128; off > 0; off >>= 1) {
    if (t < off) s[t] += s[t + off];
    __syncthreads();
  }
  if (t == 0) partial[blockIdx.x] = s[0];
}

extern "C" __global__ __launch_bounds__(512) void k_scan2(const int* __restrict__ partial,
                                                          int* __restrict__ pexcl) {
  __shared__ int s[512];
  int t = threadIdx.x;
  int v = partial[t];
  s[t] = v;
  __syncthreads();
  for (int off = 1; off < 512; off <<= 1) {
    int u = (t >= off) ? s[t - off] : 0;
    __syncthreads();
    s[t] += u;
    __syncthreads();
  }
  pexcl[t] = s[t] - v;  // exclusive
}

extern "C" __global__ __launch_bounds__(256) void k_scan3(const int* __restrict__ cnt,
                                                          const int* __restrict__ pexcl,
                                                          int* __restrict__ starts,
                                                          int* __restrict__ cursor) {
  __shared__ int s[256];
  int t = threadIdx.x;
  int i = blockIdx.x * 256 + t;
  int v = cnt[i];
  s[t] = v;
  __syncthreads();
  for (int off = 1; off < 256; off <<= 1) {
    int u = (t >= off) ? s[t - off] : 0;
    __syncthreads();
    s[t] += u;
    __syncthreads();
  }
  int excl = s[t] - v + pexcl[blockIdx.x];
  starts[i] = excl;
  cursor[i] = excl;
}

// ---------------- CSR fill: bucket edges by destination ----------------
extern "C" __global__ void k_fill(const int* __restrict__ row, const int* __restrict__ col,
                                  const float* __restrict__ dis, int* __restrict__ cursor,
                                  int* __restrict__ nbr, float* __restrict__ wn) {
  int e = blockIdx.x * 256 + threadIdx.x;
  if (e < NE) {
    int r = row[e], c = col[e];
    int pos = atomicAdd(&cursor[c], 1);
    nbr[pos] = r;
    wn[pos] = dis[r] * dis[c];
  }
}

// ---------------- GEMM1: h1 = x @ W1 ----------------
extern "C" __global__ __launch_bounds__(256) void k_gemm1(
    const float* __restrict__ x, const float* __restrict__ W1, float* __restrict__ h1) {
  __shared__ float4 wl[DD * 16];  // W1 as [k][j4], 16 KB
  int t = threadIdx.x;
  for (int i = t; i < DD * 16; i += 256) wl[i] = reinterpret_cast<const float4*>(W1)[i];
  __syncthreads();
  int row = blockIdx.x * 256 + t;
  const float4* xp = reinterpret_cast<const float4*>(x + (size_t)row * DD);
  float4 acc[16];
#pragma unroll
  for (int j = 0; j < 16; ++j) acc[j] = make_float4(0.f, 0.f, 0.f, 0.f);
#pragma unroll
  for (int kk = 0; kk < 16; ++kk) {
    float4 a = xp[kk];
#pragma unroll
    for (int j = 0; j < 16; ++j) {
      float4 w0 = wl[(4 * kk + 0) * 16 + j];
      float4 w1 = wl[(4 * kk + 1) * 16 + j];
      float4 w2 = wl[(4 * kk + 2) * 16 + j];
      float4 w3 = wl[(4 * kk + 3) * 16 + j];
      acc[j].x += a.x * w0.x + a.y * w1.x + a.z * w2.x + a.w * w3.x;
      acc[j].y += a.x * w0.y + a.y * w1.y + a.z * w2.y + a.w * w3.y;
      acc[j].z += a.x * w0.z + a.y * w1.z + a.z * w2.z + a.w * w3.z;
      acc[j].w += a.x * w0.w + a.y * w1.w + a.z * w2.w + a.w * w3.w;
    }
  }
  float4* hp = reinterpret_cast<float4*>(h1 + (size_t)row * DD);
#pragma unroll
  for (int j = 0; j < 16; ++j) hp[j] = acc[j];
}

// ---- fused: agg1 gather (wave per node) + bias + relu + @W2 -> h2 ----
extern "C" __global__ __launch_bounds__(256) void k_agg1f(
    const float* __restrict__ h1, const int* __restrict__ starts, const int* __restrict__ cnt,
    const int* __restrict__ nbr, const float* __restrict__ wn, const float* __restrict__ dis,
    const float* __restrict__ b1, const float* __restrict__ W2, float* __restrict__ h2) {
  int lane = threadIdx.x & 63;
  int node = blockIdx.x * 4 + (threadIdx.x >> 6);
  int start = starts[node];
  int deg = cnt[node];
  float di = dis[node];
  float a = h1[(size_t)node * DD + lane] * di * di;  // self-loop
  // preload up to 64 edges into lanes, broadcast via shfl
  int nb = 0;
  float w = 0.f;
  if (lane < deg) {
    nb = nbr[start + lane];
    w = wn[start + lane];
  }
  int m = deg < 64 ? deg : 64;
  for (int e = 0; e < m; ++e) {
    int r = __shfl(nb, e);
    float we = __shfl(w, e);
    a += we * h1[(size_t)r * DD + lane];
  }
  for (int e = start + 64; e < start + deg; ++e) {  // rare tail (deg > 64)
    int r = nbr[e];
    float we = wn[e];
    a += we * h1[(size_t)r * DD + lane];
  }
  // layer2 node work: z = relu(a + b1); h2 = z @ W2
  float z = fmaxf(a + b1[lane], 0.f);
  float v0 = z * W2[lane * 3 + 0];
  float v1 = z * W2[lane * 3 + 1];
  float v2 = z * W2[lane * 3 + 2];
#pragma unroll
  for (int off = 32; off > 0; off >>= 1) {
    v0 += __shfl_xor(v0, off);
    v1 += __shfl_xor(v1, off);
    v2 += __shfl_xor(v2, off);
  }
  if (lane == 0) {
    h2[node * 3 + 0] = v0;
    h2[node * 3 + 1] = v1;
    h2[node * 3 + 2] = v2;
  }
}

// ---- layer-2 aggregation: thread per node, gather h2[nbr] ----
extern "C" __global__ __launch_bounds__(256) void k_agg2(
    const float* __restrict__ h2, const int* __restrict__ starts, const int* __restrict__ cnt,
    const int* __restrict__ nbr, const float* __restrict__ wn, const float* __restrict__ dis,
    float* __restrict__ agg2) {
  int n = blockIdx.x * 256 + threadIdx.x;
  int start = starts[n];
  int deg = cnt[n];
  float di = dis[n];
  float s2 = di * di;
  float s0 = h2[n * 3 + 0] * s2;
  float s1 = h2[n * 3 + 1] * s2;
  float sS = h2[n * 3 + 2] * s2;
  for (int e = start; e < start + deg; ++e) {
    int r = nbr[e];
    float we = wn[e];
    s0 += we * h2[r * 3 + 0];
    s1 += we * h2[r * 3 + 1];
    sS += we * h2[r * 3 + 2];
  }
  agg2[n * 3 + 0] = s0;
  agg2[n * 3 + 1] = s1;
  agg2[n * 3 + 2] = sS;
}

// ---------------- mean pool over contiguous 4096-node graphs + b2 ----------------
extern "C" __global__ __launch_bounds__(256) void k_pool(
    const float* __restrict__ agg2, const float* __restrict__ b2, float* __restrict__ out) {
  __shared__ float red[3][256];
  int g = blockIdx.x, t = threadIdx.x;
  float s0 = 0.f, s1 = 0.f, s2 = 0.f;
  for (int n = t; n < NPG; n += 256) {
    int i = g * NPG + n;
    s0 += agg2[i * 3 + 0];
    s1 += agg2[i * 3 + 1];
    s2 += agg2[i * 3 + 2];
  }
  red[0][t] = s0; red[1][t] = s1; red[2][t] = s2;
  __syncthreads();
  for (int off = 128; off > 0; off >>= 1) {
    if (t < off) {
      red[0][t] += red[0][t + off];
      red[1][t] += red[1][t + off];
      red[2][t] += red[2][t + off];
    }
    __syncthreads();
  }
  if (t == 0) {
    float inv = 1.0f / (float)NPG;
    out[g * 3 + 0] = red[0][0] * inv + b2[0];
    out[g * 3 + 1] = red[1][0] * inv + b2[1];
    out[g * 3 + 2] = red[2][0] * inv + b2[2];
  }
}

extern "C" void kernel_launch(void* const* d_in, const int* in_sizes, int n_in,
                              void* d_out, int out_size, void* d_ws, size_t ws_size,
                              hipStream_t stream) {
  const float* x  = (const float*)d_in[0];
  const int*   ei = (const int*)d_in[1];
  const float* W1 = (const float*)d_in[3];
  const float* b1 = (const float*)d_in[4];
  const float* W2 = (const float*)d_in[5];
  const float* b2 = (const float*)d_in[6];
  const int* row = ei;
  const int* col = ei + NE;
  float* out = (float*)d_out;

  // workspace layout (byte offsets)
  char* ws = (char*)d_ws;
  int*   cnt     = (int*)(ws + 0);              // 512 KB
  float* dis     = (float*)(ws + (1u << 19));   // 512 KB
  int*   starts  = (int*)(ws + (2u << 19));     // 512 KB
  int*   cursor  = (int*)(ws + (3u << 19));     // 512 KB
  int*   partial = (int*)(ws + (4u << 19));     // 2 KB
  int*   pexcl   = (int*)(ws + (4u << 19) + 4096);
  int*   nbr     = (int*)(ws + (5u << 19));     // 4 MB
  float* wn      = (float*)(ws + (5u << 19) + (1u << 22));          // 4 MB
  float* h1      = (float*)(ws + (5u << 19) + (2u << 22));          // 32 MB
  float* h2      = (float*)(ws + (5u << 19) + (2u << 22) + (1u << 25));  // 1.5 MB
  float* agg2    = (float*)(ws + (5u << 19) + (2u << 22) + (1u << 25) + (1u << 21));

  hipMemsetAsync(cnt, 0, NN * sizeof(int), stream);
  k_count<<<NE / 256, 256, 0, stream>>>(col, cnt);
  k_dis<<<NN / 256, 256, 0, stream>>>(cnt, dis);
  k_scan1<<<SCAN_B, 256, 0, stream>>>(cnt, partial);
  k_scan2<<<1, 512, 0, stream>>>(partial, pexcl);
  k_scan3<<<SCAN_B, 256, 0, stream>>>(cnt, pexcl, starts, cursor);
  k_fill<<<NE / 256, 256, 0, stream>>>(row, col, dis, cursor, nbr, wn);
  k_gemm1<<<NN / 256, 256, 0, stream>>>(x, W1, h1);
  k_agg1f<<<NN / 4, 256, 0, stream>>>(h1, starts, cnt, nbr, wn, dis, b1, W2, h2);
  k_agg2<<<NN / 256, 256, 0, stream>>>(h2, starts, cnt, nbr, wn, dis, agg2);
  k_pool<<<NG, 256, 0, stream>>>(agg2, b2, out);
}